// Round 1
// baseline (647.683 us; speedup 1.0000x reference)
//
#include <hip/hip_runtime.h>
#include <hip/hip_bf16.h>

#define S 4096
#define DMODEL 1024
#define DK 128

// ---------------------------------------------------------------------------
// Kernel 1: QKV projection.  grid = (S/16, 3 [Q,K,V]), block = 128 threads.
// Computes P = X @ W^T + b for one 16-row tile. Q and V stored row-major
// [S][DK]; K stored TRANSPOSED [DK][S] so the attention QK dot is
// lane-coalesced.
// Tiling: BM=16, BN=128, BK=32. Per-thread 4 rows x 4 cols register tile.
// ---------------------------------------------------------------------------
__global__ __launch_bounds__(128) void proj_kernel(
    const float* __restrict__ X,
    const float* __restrict__ Wq, const float* __restrict__ bq,
    const float* __restrict__ Wk, const float* __restrict__ bk,
    const float* __restrict__ Wv, const float* __restrict__ bv,
    float* __restrict__ Qo, float* __restrict__ Kt, float* __restrict__ Vo)
{
    const int sel  = blockIdx.y;                 // 0=Q, 1=K, 2=V
    const float* __restrict__ W    = (sel == 0) ? Wq : (sel == 1) ? Wk : Wv;
    const float* __restrict__ bias = (sel == 0) ? bq : (sel == 1) ? bk : bv;
    const int row0 = blockIdx.x * 16;
    const int t    = threadIdx.x;

    __shared__ float Xs[16][33];     // [row][k]   (+1 pad)
    __shared__ float Ws[32][132];    // [k][n]     (padded row)

    const int ty = t >> 5;          // 0..3  -> rows ty*4 .. ty*4+3
    const int tx = t & 31;          // cols tx + 32*j, j=0..3

    float acc[4][4];
    #pragma unroll
    for (int r = 0; r < 4; ++r)
        #pragma unroll
        for (int j = 0; j < 4; ++j) acc[r][j] = 0.f;

    for (int k0 = 0; k0 < DMODEL; k0 += 32) {
        // --- load X tile 16x32 (512 floats = 128 float4, one per thread)
        {
            const int r = t >> 3, c = (t & 7) * 4;
            const float4 x = *reinterpret_cast<const float4*>(
                &X[(size_t)(row0 + r) * DMODEL + k0 + c]);
            Xs[r][c + 0] = x.x; Xs[r][c + 1] = x.y;
            Xs[r][c + 2] = x.z; Xs[r][c + 3] = x.w;
        }
        // --- load W tile 128x32 -> Ws[k][n]  (4096 floats = 1024 float4)
        #pragma unroll
        for (int i = 0; i < 8; ++i) {
            const int e = t + i * 128;
            const int n = e >> 3, c = (e & 7) * 4;
            const float4 w = *reinterpret_cast<const float4*>(
                &W[(size_t)n * DMODEL + k0 + c]);
            Ws[c + 0][n] = w.x; Ws[c + 1][n] = w.y;
            Ws[c + 2][n] = w.z; Ws[c + 3][n] = w.w;
        }
        __syncthreads();

        #pragma unroll
        for (int kk = 0; kk < 32; ++kk) {
            float a[4], b[4];
            #pragma unroll
            for (int r = 0; r < 4; ++r) a[r] = Xs[ty * 4 + r][kk];
            #pragma unroll
            for (int j = 0; j < 4; ++j) b[j] = Ws[kk][tx + 32 * j];
            #pragma unroll
            for (int r = 0; r < 4; ++r)
                #pragma unroll
                for (int j = 0; j < 4; ++j) acc[r][j] += a[r] * b[j];
        }
        __syncthreads();
    }

    #pragma unroll
    for (int r = 0; r < 4; ++r) {
        const int row = row0 + ty * 4 + r;
        #pragma unroll
        for (int j = 0; j < 4; ++j) {
            const int n = tx + 32 * j;
            const float v = acc[r][j] + bias[n];
            if (sel == 0)      Qo[(size_t)row * DK + n] = v;
            else if (sel == 1) Kt[(size_t)n * S + row]  = v;   // transposed
            else               Vo[(size_t)row * DK + n] = v;
        }
    }
}

// ---------------------------------------------------------------------------
// Kernel 2: causal flash attention, fp32. One wave (64 threads) per query
// row; grid = S blocks. Heavy rows dispatched first for load balance.
// Online softmax; lane j scores key base+j (Kt coalesced); PV via readlane
// broadcast, lane owns output dims {2*lane, 2*lane+1}.
// ---------------------------------------------------------------------------
__global__ __launch_bounds__(64) void attn_kernel(
    const float* __restrict__ Q, const float* __restrict__ Kt,
    const float* __restrict__ V, float* __restrict__ Out)
{
    const int row  = S - 1 - blockIdx.x;   // heaviest rows first
    const int lane = threadIdx.x;          // 0..63

    __shared__ float Qs[DK];
    Qs[lane]      = Q[(size_t)row * DK + lane];
    Qs[lane + 64] = Q[(size_t)row * DK + lane + 64];
    __syncthreads();

    const float scale = 0.08838834764831845f;  // 1/sqrt(128)
    float  m = -1e30f, lsum = 0.f;
    float2 acc = make_float2(0.f, 0.f);

    const int nchunks = (row >> 6) + 1;        // keys 0..row in chunks of 64

    for (int t = 0; t < nchunks; ++t) {
        const int base = t << 6;
        const int j    = base + lane;

        // ---- scores: s = (Q[row] . K[j]) * scale
        float s = 0.f;
        const float* __restrict__ kp = Kt + base + lane;  // Kt[kk][j]
        #pragma unroll 8
        for (int kk = 0; kk < DK; ++kk)
            s += Qs[kk] * kp[(size_t)kk * S];
        s *= scale;
        if (j > row) s = -1e30f;               // causal mask

        // ---- online softmax update
        float cm = s;
        #pragma unroll
        for (int off = 32; off; off >>= 1)
            cm = fmaxf(cm, __shfl_xor(cm, off));
        const float mnew = fmaxf(m, cm);
        const float p    = __expf(s - mnew);   // masked lanes -> 0
        float ps = p;
        #pragma unroll
        for (int off = 32; off; off >>= 1)
            ps += __shfl_xor(ps, off);
        const float corr = __expf(m - mnew);
        lsum  = lsum * corr + ps;
        acc.x *= corr; acc.y *= corr;
        m = mnew;

        // ---- accumulate P @ V (lane owns dims 2*lane, 2*lane+1)
        #pragma unroll 16
        for (int j2 = 0; j2 < 64; ++j2) {
            const float  pj = __shfl(p, j2);
            const float2 v  = reinterpret_cast<const float2*>(
                V + (size_t)(base + j2) * DK)[lane];
            acc.x += pj * v.x;
            acc.y += pj * v.y;
        }
    }

    const float inv = 1.f / lsum;
    reinterpret_cast<float2*>(Out + (size_t)row * DK)[lane] =
        make_float2(acc.x * inv, acc.y * inv);
}

// ---------------------------------------------------------------------------
extern "C" void kernel_launch(void* const* d_in, const int* in_sizes, int n_in,
                              void* d_out, int out_size, void* d_ws, size_t ws_size,
                              hipStream_t stream)
{
    (void)in_sizes; (void)n_in; (void)out_size; (void)ws_size;
    const float* X  = (const float*)d_in[0];
    const float* Wq = (const float*)d_in[1];
    const float* bq = (const float*)d_in[2];
    const float* Wk = (const float*)d_in[3];
    const float* bk = (const float*)d_in[4];
    const float* Wv = (const float*)d_in[5];
    const float* bv = (const float*)d_in[6];
    float* out = (float*)d_out;

    float* Qw  = (float*)d_ws;            // [S][DK]
    float* Ktw = Qw + (size_t)S * DK;     // [DK][S]  (K transposed)
    float* Vw  = Ktw + (size_t)S * DK;    // [S][DK]
    // workspace use: 3 * 4096 * 128 * 4B = 6 MiB

    proj_kernel<<<dim3(S / 16, 3), 128, 0, stream>>>(
        X, Wq, bq, Wk, bk, Wv, bv, Qw, Ktw, Vw);
    attn_kernel<<<S, 64, 0, stream>>>(Qw, Ktw, Vw, out);
}

// Round 2
// 209.515 us; speedup vs baseline: 3.0913x; 3.0913x over previous
//
#include <hip/hip_runtime.h>
#include <hip/hip_bf16.h>

#define S 4096
#define DMODEL 1024
#define DK 128

typedef __attribute__((ext_vector_type(8))) short  short8;   // 8 x bf16 (4 VGPRs)
typedef __attribute__((ext_vector_type(4))) float  f32x4;    // MFMA accumulator

__device__ __forceinline__ unsigned short f2bf(float f) {
    return __builtin_bit_cast(unsigned short, __float2bfloat16(f));
}

__device__ __forceinline__ short8 cvt8(float4 a, float4 b) {
    short8 v;
    v[0] = (short)f2bf(a.x); v[1] = (short)f2bf(a.y);
    v[2] = (short)f2bf(a.z); v[3] = (short)f2bf(a.w);
    v[4] = (short)f2bf(b.x); v[5] = (short)f2bf(b.y);
    v[6] = (short)f2bf(b.z); v[7] = (short)f2bf(b.w);
    return v;
}

// ---------------------------------------------------------------------------
// QKV projection, bf16 MFMA.  grid = (S/32, 3), block = 256 (4 waves).
// Wave w: rows rbase..rbase+15 (w&1), cols n0..n0+63 (w>>1). K-loop step 32.
// A-frag: X[row=lane&15][k0+8*(lane>>4)+i] (fp32->bf16 cvt in flight).
// B-frag: W is [DK][DMODEL] = B^T row-major, so W rows load directly.
// Outputs Q,K,V bf16 row-major [S][DK].
// ---------------------------------------------------------------------------
__global__ __launch_bounds__(256) void proj_mfma(
    const float* __restrict__ X,
    const float* __restrict__ Wq, const float* __restrict__ bq,
    const float* __restrict__ Wk, const float* __restrict__ bk,
    const float* __restrict__ Wv, const float* __restrict__ bv,
    unsigned short* __restrict__ Qb, unsigned short* __restrict__ Kb,
    unsigned short* __restrict__ Vb)
{
    const int sel = blockIdx.y;
    const float* __restrict__ W    = sel == 0 ? Wq : sel == 1 ? Wk : Wv;
    const float* __restrict__ bias = sel == 0 ? bq : sel == 1 ? bk : bv;
    unsigned short* __restrict__ Out = sel == 0 ? Qb : sel == 1 ? Kb : Vb;

    const int tid = threadIdx.x;
    const int w = tid >> 6, lane = tid & 63;
    const int li = lane & 15, gl = lane >> 4;
    const int rbase = blockIdx.x * 32 + (w & 1) * 16;
    const int n0    = (w >> 1) * 64;
    const int rowA  = rbase + li;

    f32x4 acc[4];
    #pragma unroll
    for (int j = 0; j < 4; ++j)
        #pragma unroll
        for (int r = 0; r < 4; ++r) acc[j][r] = 0.f;

    for (int k0 = 0; k0 < DMODEL; k0 += 32) {
        const float4* xp = (const float4*)&X[(size_t)rowA * DMODEL + k0 + 8 * gl];
        const short8 a = cvt8(xp[0], xp[1]);
        #pragma unroll
        for (int j = 0; j < 4; ++j) {
            const float4* wp =
                (const float4*)&W[(size_t)(n0 + 16 * j + li) * DMODEL + k0 + 8 * gl];
            const short8 b = cvt8(wp[0], wp[1]);
            acc[j] = __builtin_amdgcn_mfma_f32_16x16x32_bf16(a, b, acc[j], 0, 0, 0);
        }
    }

    #pragma unroll
    for (int j = 0; j < 4; ++j)
        #pragma unroll
        for (int r = 0; r < 4; ++r) {
            const int row = rbase + 4 * gl + r;
            const int col = n0 + 16 * j + li;
            Out[(size_t)row * DK + col] = f2bf(acc[j][r] + bias[col]);
        }
}

// ---------------------------------------------------------------------------
// V [S][DK] bf16 -> Vt [DK][S] bf16 (coalesced LDS tile transpose).
// grid (S/64, DK/64), block 256.
// ---------------------------------------------------------------------------
__global__ __launch_bounds__(256) void transpose_v(
    const unsigned short* __restrict__ Vb, unsigned short* __restrict__ Vt)
{
    __shared__ unsigned short tile[64][72];   // +8 pad
    const int s0 = blockIdx.x * 64, d0 = blockIdx.y * 64;
    const int t = threadIdx.x;
    const int r = t >> 2, cc = (t & 3) * 16;

    const short8* src = (const short8*)&Vb[(size_t)(s0 + r) * DK + d0 + cc];
    const short8 a = src[0], b = src[1];
    #pragma unroll
    for (int i = 0; i < 8; ++i) {
        tile[r][cc + i]     = (unsigned short)a[i];
        tile[r][cc + 8 + i] = (unsigned short)b[i];
    }
    __syncthreads();

    short8 o0, o1;
    #pragma unroll
    for (int i = 0; i < 8; ++i) {
        o0[i] = (short)tile[cc + i][r];
        o1[i] = (short)tile[cc + 8 + i][r];
    }
    short8* dst = (short8*)&Vt[(size_t)(d0 + r) * S + s0 + cc];
    dst[0] = o0; dst[1] = o1;
}

// ---------------------------------------------------------------------------
// Flash attention, bf16 MFMA. 1 wave per block, 16 q-rows per block.
// Causal-balanced key split: q-tile qt in [64g, 64g+64) gets g+1 chunks of
// <=1024 keys -> 640 equal-work blocks. Partial (O,m,l) per block; merged by
// merge_kernel. K/V read direct from global (1 MB each, L2-resident).
// Per 32-key iter: 8 QK MFMAs, online softmax in D-layout (row=reg,
// 16-lane shfl reduce), P bounce via padded LDS -> A-frag, 8 PV MFMAs.
// ---------------------------------------------------------------------------
__global__ __launch_bounds__(64) void attn_mfma(
    const unsigned short* __restrict__ Qb,
    const unsigned short* __restrict__ Kb,
    const unsigned short* __restrict__ Vt,
    float* __restrict__ OP, float* __restrict__ ML)
{
    const int b = blockIdx.x;
    int g;
    if (b < 64) g = 0; else if (b < 192) g = 1; else if (b < 384) g = 2; else g = 3;
    const int off = b - 32 * g * (g + 1);
    const int qt  = 64 * g + off / (g + 1);
    const int c   = off % (g + 1);
    const int kstart = c * 1024;
    const int kend   = min((c + 1) * 1024, 16 * qt + 16);

    const int lane = threadIdx.x, li = lane & 15, gl = lane >> 4;
    const int qrow = 16 * qt + li;

    __shared__ unsigned short Pl[16][40];     // 80B rows: b128 reads conflict-free

    short8 aq[4];
    #pragma unroll
    for (int s = 0; s < 4; ++s)
        aq[s] = *(const short8*)&Qb[(size_t)qrow * DK + 32 * s + 8 * gl];

    f32x4 accv[8];
    #pragma unroll
    for (int n = 0; n < 8; ++n)
        #pragma unroll
        for (int r = 0; r < 4; ++r) accv[n][r] = 0.f;

    float mrow[4] = {-1e30f, -1e30f, -1e30f, -1e30f};
    float lrow[4] = {0.f, 0.f, 0.f, 0.f};
    const float scale = 0.08838834764831845f;  // 1/sqrt(128)

    for (int kb = kstart; kb < kend; kb += 32) {
        // ---- issue all global loads up front (V latency hides under QK+softmax)
        short8 bk[2][4], bv[8];
        #pragma unroll
        for (int kt = 0; kt < 2; ++kt)
            #pragma unroll
            for (int s = 0; s < 4; ++s)
                bk[kt][s] = *(const short8*)
                    &Kb[(size_t)(kb + 16 * kt + li) * DK + 32 * s + 8 * gl];
        #pragma unroll
        for (int n = 0; n < 8; ++n)
            bv[n] = *(const short8*)&Vt[(size_t)(16 * n + li) * S + kb + 8 * gl];

        // ---- QK^T: scores [16q][32k] as two 16x16 tiles
        f32x4 sc[2];
        #pragma unroll
        for (int kt = 0; kt < 2; ++kt)
            #pragma unroll
            for (int r = 0; r < 4; ++r) sc[kt][r] = 0.f;
        #pragma unroll
        for (int kt = 0; kt < 2; ++kt)
            #pragma unroll
            for (int s = 0; s < 4; ++s)
                sc[kt] = __builtin_amdgcn_mfma_f32_16x16x32_bf16(
                    aq[s], bk[kt][s], sc[kt], 0, 0, 0);

        // ---- scale + causal mask (D-layout: row q = 4*gl+r, col key = li)
        float p[2][4];
        #pragma unroll
        for (int kt = 0; kt < 2; ++kt)
            #pragma unroll
            for (int r = 0; r < 4; ++r) {
                const int key = kb + 16 * kt + li;
                const int q   = 16 * qt + 4 * gl + r;
                p[kt][r] = (key > q) ? -1e30f : sc[kt][r] * scale;
            }

        // ---- online softmax, per row r (16-lane reduce within group)
        #pragma unroll
        for (int r = 0; r < 4; ++r) {
            float t = fmaxf(p[0][r], p[1][r]);
            t = fmaxf(t, __shfl_xor(t, 1));
            t = fmaxf(t, __shfl_xor(t, 2));
            t = fmaxf(t, __shfl_xor(t, 4));
            t = fmaxf(t, __shfl_xor(t, 8));
            const float mnew = fmaxf(mrow[r], t);
            const float corr = __expf(mrow[r] - mnew);
            p[0][r] = __expf(p[0][r] - mnew);
            p[1][r] = __expf(p[1][r] - mnew);
            float ps = p[0][r] + p[1][r];
            ps += __shfl_xor(ps, 1);
            ps += __shfl_xor(ps, 2);
            ps += __shfl_xor(ps, 4);
            ps += __shfl_xor(ps, 8);
            lrow[r] = lrow[r] * corr + ps;
            mrow[r] = mnew;
            #pragma unroll
            for (int n = 0; n < 8; ++n) accv[n][r] *= corr;
        }

        // ---- P (D-layout) -> LDS bf16 -> reread as A-fragment
        #pragma unroll
        for (int kt = 0; kt < 2; ++kt)
            #pragma unroll
            for (int r = 0; r < 4; ++r)
                Pl[4 * gl + r][16 * kt + li] = f2bf(p[kt][r]);
        __syncthreads();
        const short8 pa = *(const short8*)&Pl[li][8 * gl];
        __syncthreads();

        // ---- PV: out[16q][128dv] += P[16][32] @ V[32][128]
        #pragma unroll
        for (int n = 0; n < 8; ++n)
            accv[n] = __builtin_amdgcn_mfma_f32_16x16x32_bf16(pa, bv[n], accv[n], 0, 0, 0);
    }

    // ---- store unnormalized partial O + (m, l)
    #pragma unroll
    for (int n = 0; n < 8; ++n)
        #pragma unroll
        for (int r = 0; r < 4; ++r)
            OP[((size_t)b * 16 + 4 * gl + r) * DK + 16 * n + li] = accv[n][r];
    if (li == 0) {
        #pragma unroll
        for (int r = 0; r < 4; ++r) {
            ML[((size_t)b * 16 + 4 * gl + r) * 2 + 0] = mrow[r];
            ML[((size_t)b * 16 + 4 * gl + r) * 2 + 1] = lrow[r];
        }
    }
}

// ---------------------------------------------------------------------------
// Merge <=4 causal-split partials per q-row. grid = S blocks, block = DK.
// ---------------------------------------------------------------------------
__global__ __launch_bounds__(DK) void merge_kernel(
    const float* __restrict__ OP, const float* __restrict__ ML,
    float* __restrict__ out)
{
    const int row = blockIdx.x, dv = threadIdx.x;
    const int qt = row >> 4, ql = row & 15;
    const int g  = qt >> 6;
    const int base = 32 * g * (g + 1) + (qt - 64 * g) * (g + 1);

    float M = -1e30f;
    for (int c = 0; c <= g; ++c)
        M = fmaxf(M, ML[((size_t)(base + c) * 16 + ql) * 2]);
    float L = 0.f, o = 0.f;
    for (int c = 0; c <= g; ++c) {
        const float mc = ML[((size_t)(base + c) * 16 + ql) * 2 + 0];
        const float lc = ML[((size_t)(base + c) * 16 + ql) * 2 + 1];
        const float wgt = __expf(mc - M);
        L += lc * wgt;
        o += wgt * OP[((size_t)(base + c) * 16 + ql) * DK + dv];
    }
    out[(size_t)row * DK + dv] = o / L;
}

// ---------------------------------------------------------------------------
extern "C" void kernel_launch(void* const* d_in, const int* in_sizes, int n_in,
                              void* d_out, int out_size, void* d_ws, size_t ws_size,
                              hipStream_t stream)
{
    (void)in_sizes; (void)n_in; (void)out_size; (void)ws_size;
    const float* X  = (const float*)d_in[0];
    const float* Wq = (const float*)d_in[1];
    const float* bq = (const float*)d_in[2];
    const float* Wk = (const float*)d_in[3];
    const float* bk = (const float*)d_in[4];
    const float* Wv = (const float*)d_in[5];
    const float* bv = (const float*)d_in[6];
    float* out = (float*)d_out;

    // workspace layout (~9.6 MB)
    unsigned short* Qb = (unsigned short*)d_ws;          // [S][DK] bf16
    unsigned short* Kb = Qb + (size_t)S * DK;            // [S][DK] bf16
    unsigned short* Vb = Kb + (size_t)S * DK;            // [S][DK] bf16
    unsigned short* Vt = Vb + (size_t)S * DK;            // [DK][S] bf16
    float* OP = (float*)(Vt + (size_t)S * DK);           // [640][16][DK] f32
    float* ML = OP + (size_t)640 * 16 * DK;              // [640][16][2]  f32

    proj_mfma<<<dim3(S / 32, 3), 256, 0, stream>>>(
        X, Wq, bq, Wk, bk, Wv, bv, Qb, Kb, Vb);
    transpose_v<<<dim3(S / 64, DK / 64), 256, 0, stream>>>(Vb, Vt);
    attn_mfma<<<640, 64, 0, stream>>>(Qb, Kb, Vt, OP, ML);
    merge_kernel<<<S, DK, 0, stream>>>(OP, ML, out);
}

// Round 3
// 159.631 us; speedup vs baseline: 4.0574x; 1.3125x over previous
//
#include <hip/hip_runtime.h>
#include <hip/hip_bf16.h>

#define S 4096
#define DMODEL 1024
#define DK 128

typedef __attribute__((ext_vector_type(8))) short  short8;   // 8 x bf16 (4 VGPRs)
typedef __attribute__((ext_vector_type(4))) float  f32x4;    // MFMA accumulator

__device__ __forceinline__ unsigned short f2bf(float f) {
    return __builtin_bit_cast(unsigned short, __float2bfloat16(f));
}

__device__ __forceinline__ short8 cvt8(float4 a, float4 b) {
    short8 v;
    v[0] = (short)f2bf(a.x); v[1] = (short)f2bf(a.y);
    v[2] = (short)f2bf(a.z); v[3] = (short)f2bf(a.w);
    v[4] = (short)f2bf(b.x); v[5] = (short)f2bf(b.y);
    v[6] = (short)f2bf(b.z); v[7] = (short)f2bf(b.w);
    return v;
}

// ---------------------------------------------------------------------------
// Convert X [S][DMODEL] f32 -> Xb bf16 and Wq|Wk|Wv [DK][DMODEL] f32 -> Wb
// bf16 (concatenated). One-shot, HBM-bound. 8 elems/thread.
// items: X = 524288, W = 3*16384 = 49152; total 573440 = 2240 * 256.
// ---------------------------------------------------------------------------
__global__ __launch_bounds__(256) void cvt_kernel(
    const float* __restrict__ X,
    const float* __restrict__ Wq, const float* __restrict__ Wk,
    const float* __restrict__ Wv,
    unsigned short* __restrict__ Xb, unsigned short* __restrict__ Wb)
{
    const int i = blockIdx.x * 256 + threadIdx.x;
    const float* __restrict__ src;
    unsigned short* __restrict__ dst;
    size_t off;
    if (i < 524288) {
        src = X; dst = Xb; off = (size_t)i * 8;
    } else {
        const int j   = i - 524288;
        const int sel = j >> 14, jj = j & 16383;
        src = sel == 0 ? Wq : sel == 1 ? Wk : Wv;
        dst = Wb + (size_t)sel * DK * DMODEL;
        off = (size_t)jj * 8;
    }
    const float4 a = *(const float4*)(src + off);
    const float4 b = *(const float4*)(src + off + 4);
    *(short8*)(dst + off) = cvt8(a, b);
}

// ---------------------------------------------------------------------------
// QKV projection GEMM, bf16 inputs. grid = (S/16, 3), block = 256 (4 waves).
// Block: 16 rows x 128 cols. Wave w: cols 32w..32w+31 (2 MFMA tiles).
// Per k-step(32): 1 A load + 2 B loads + 2 MFMAs. 768 blocks -> 12 waves/CU.
// ---------------------------------------------------------------------------
__global__ __launch_bounds__(256) void proj_gemm(
    const unsigned short* __restrict__ Xb, const unsigned short* __restrict__ Wb,
    const float* __restrict__ bq, const float* __restrict__ bk,
    const float* __restrict__ bv,
    unsigned short* __restrict__ Qb, unsigned short* __restrict__ Kb,
    unsigned short* __restrict__ Vb)
{
    const int sel = blockIdx.y;
    const float* __restrict__ bias = sel == 0 ? bq : sel == 1 ? bk : bv;
    unsigned short* __restrict__ Out = sel == 0 ? Qb : sel == 1 ? Kb : Vb;
    const unsigned short* __restrict__ wbase = Wb + (size_t)sel * DK * DMODEL;

    const int tid = threadIdx.x, w = tid >> 6, lane = tid & 63;
    const int li = lane & 15, gl = lane >> 4;
    const int r0 = blockIdx.x * 16;
    const int n0 = w * 32;

    f32x4 acc[2];
    #pragma unroll
    for (int j = 0; j < 2; ++j)
        #pragma unroll
        for (int r = 0; r < 4; ++r) acc[j][r] = 0.f;

    const unsigned short* ap = &Xb[(size_t)(r0 + li) * DMODEL + 8 * gl];
    const unsigned short* bp0 = &wbase[(size_t)(n0 + li) * DMODEL + 8 * gl];
    const unsigned short* bp1 = &wbase[(size_t)(n0 + 16 + li) * DMODEL + 8 * gl];

    #pragma unroll 4
    for (int k0 = 0; k0 < DMODEL; k0 += 32) {
        const short8 a  = *(const short8*)(ap + k0);
        const short8 b0 = *(const short8*)(bp0 + k0);
        const short8 b1 = *(const short8*)(bp1 + k0);
        acc[0] = __builtin_amdgcn_mfma_f32_16x16x32_bf16(a, b0, acc[0], 0, 0, 0);
        acc[1] = __builtin_amdgcn_mfma_f32_16x16x32_bf16(a, b1, acc[1], 0, 0, 0);
    }

    #pragma unroll
    for (int j = 0; j < 2; ++j)
        #pragma unroll
        for (int r = 0; r < 4; ++r) {
            const int row = r0 + 4 * gl + r;
            const int col = n0 + 16 * j + li;
            Out[(size_t)row * DK + col] = f2bf(acc[j][r] + bias[col]);
        }
}

// ---------------------------------------------------------------------------
// V [S][DK] bf16 -> Vt [DK][S] bf16 (coalesced LDS tile transpose).
// grid (S/64, DK/64), block 256.
// ---------------------------------------------------------------------------
__global__ __launch_bounds__(256) void transpose_v(
    const unsigned short* __restrict__ Vb, unsigned short* __restrict__ Vt)
{
    __shared__ unsigned short tile[64][72];   // +8 pad
    const int s0 = blockIdx.x * 64, d0 = blockIdx.y * 64;
    const int t = threadIdx.x;
    const int r = t >> 2, cc = (t & 3) * 16;

    const short8* src = (const short8*)&Vb[(size_t)(s0 + r) * DK + d0 + cc];
    const short8 a = src[0], b = src[1];
    #pragma unroll
    for (int i = 0; i < 8; ++i) {
        tile[r][cc + i]     = (unsigned short)a[i];
        tile[r][cc + 8 + i] = (unsigned short)b[i];
    }
    __syncthreads();

    short8 o0, o1;
    #pragma unroll
    for (int i = 0; i < 8; ++i) {
        o0[i] = (short)tile[cc + i][r];
        o1[i] = (short)tile[cc + 8 + i][r];
    }
    short8* dst = (short8*)&Vt[(size_t)(d0 + r) * S + s0 + cc];
    dst[0] = o0; dst[1] = o1;
}

// ---------------------------------------------------------------------------
// Flash attention, bf16 MFMA. 1 wave per block, 16 q-rows per block.
// Causal-balanced key split, chunk = 512 keys: q-tile qt (group g = qt>>5)
// gets g+1 chunks -> 1152 blocks (4.5 waves/CU). Partial (O,m,l) per block.
// ---------------------------------------------------------------------------
__global__ __launch_bounds__(64) void attn_mfma(
    const unsigned short* __restrict__ Qb,
    const unsigned short* __restrict__ Kb,
    const unsigned short* __restrict__ Vt,
    float* __restrict__ OP, float* __restrict__ ML)
{
    const int b = blockIdx.x;
    int g;
    if      (b <  32) g = 0; else if (b <  96) g = 1;
    else if (b < 192) g = 2; else if (b < 320) g = 3;
    else if (b < 480) g = 4; else if (b < 672) g = 5;
    else if (b < 896) g = 6; else               g = 7;
    const int off = b - 16 * g * (g + 1);
    const int qt  = 32 * g + off / (g + 1);
    const int c   = off % (g + 1);
    const int kstart = c * 512;
    const int kend   = min((c + 1) * 512, 16 * qt + 16);

    const int lane = threadIdx.x, li = lane & 15, gl = lane >> 4;
    const int qrow = 16 * qt + li;

    __shared__ unsigned short Pl[16][40];     // 80B rows: b128 reads conflict-free

    short8 aq[4];
    #pragma unroll
    for (int s = 0; s < 4; ++s)
        aq[s] = *(const short8*)&Qb[(size_t)qrow * DK + 32 * s + 8 * gl];

    f32x4 accv[8];
    #pragma unroll
    for (int n = 0; n < 8; ++n)
        #pragma unroll
        for (int r = 0; r < 4; ++r) accv[n][r] = 0.f;

    float mrow[4] = {-1e30f, -1e30f, -1e30f, -1e30f};
    float lrow[4] = {0.f, 0.f, 0.f, 0.f};
    const float scale = 0.08838834764831845f;  // 1/sqrt(128)

    for (int kb = kstart; kb < kend; kb += 32) {
        // ---- issue all global loads up front (V latency hides under QK+softmax)
        short8 bk[2][4], bv[8];
        #pragma unroll
        for (int kt = 0; kt < 2; ++kt)
            #pragma unroll
            for (int s = 0; s < 4; ++s)
                bk[kt][s] = *(const short8*)
                    &Kb[(size_t)(kb + 16 * kt + li) * DK + 32 * s + 8 * gl];
        #pragma unroll
        for (int n = 0; n < 8; ++n)
            bv[n] = *(const short8*)&Vt[(size_t)(16 * n + li) * S + kb + 8 * gl];

        // ---- QK^T: scores [16q][32k] as two 16x16 tiles
        f32x4 sc[2];
        #pragma unroll
        for (int kt = 0; kt < 2; ++kt)
            #pragma unroll
            for (int r = 0; r < 4; ++r) sc[kt][r] = 0.f;
        #pragma unroll
        for (int kt = 0; kt < 2; ++kt)
            #pragma unroll
            for (int s = 0; s < 4; ++s)
                sc[kt] = __builtin_amdgcn_mfma_f32_16x16x32_bf16(
                    aq[s], bk[kt][s], sc[kt], 0, 0, 0);

        // ---- scale + causal mask (D-layout: row q = 4*gl+r, col key = li)
        float p[2][4];
        #pragma unroll
        for (int kt = 0; kt < 2; ++kt)
            #pragma unroll
            for (int r = 0; r < 4; ++r) {
                const int key = kb + 16 * kt + li;
                const int q   = 16 * qt + 4 * gl + r;
                p[kt][r] = (key > q) ? -1e30f : sc[kt][r] * scale;
            }

        // ---- online softmax, per row r (16-lane reduce within group)
        #pragma unroll
        for (int r = 0; r < 4; ++r) {
            float t = fmaxf(p[0][r], p[1][r]);
            t = fmaxf(t, __shfl_xor(t, 1));
            t = fmaxf(t, __shfl_xor(t, 2));
            t = fmaxf(t, __shfl_xor(t, 4));
            t = fmaxf(t, __shfl_xor(t, 8));
            const float mnew = fmaxf(mrow[r], t);
            const float corr = __expf(mrow[r] - mnew);
            p[0][r] = __expf(p[0][r] - mnew);
            p[1][r] = __expf(p[1][r] - mnew);
            float ps = p[0][r] + p[1][r];
            ps += __shfl_xor(ps, 1);
            ps += __shfl_xor(ps, 2);
            ps += __shfl_xor(ps, 4);
            ps += __shfl_xor(ps, 8);
            lrow[r] = lrow[r] * corr + ps;
            mrow[r] = mnew;
            #pragma unroll
            for (int n = 0; n < 8; ++n) accv[n][r] *= corr;
        }

        // ---- P (D-layout) -> LDS bf16 -> reread as A-fragment
        #pragma unroll
        for (int kt = 0; kt < 2; ++kt)
            #pragma unroll
            for (int r = 0; r < 4; ++r)
                Pl[4 * gl + r][16 * kt + li] = f2bf(p[kt][r]);
        __syncthreads();
        const short8 pa = *(const short8*)&Pl[li][8 * gl];
        __syncthreads();

        // ---- PV: out[16q][128dv] += P[16][32] @ V[32][128]
        #pragma unroll
        for (int n = 0; n < 8; ++n)
            accv[n] = __builtin_amdgcn_mfma_f32_16x16x32_bf16(pa, bv[n], accv[n], 0, 0, 0);
    }

    // ---- store unnormalized partial O + (m, l)
    #pragma unroll
    for (int n = 0; n < 8; ++n)
        #pragma unroll
        for (int r = 0; r < 4; ++r)
            OP[((size_t)b * 16 + 4 * gl + r) * DK + 16 * n + li] = accv[n][r];
    if (li == 0) {
        #pragma unroll
        for (int r = 0; r < 4; ++r) {
            ML[((size_t)b * 16 + 4 * gl + r) * 2 + 0] = mrow[r];
            ML[((size_t)b * 16 + 4 * gl + r) * 2 + 1] = lrow[r];
        }
    }
}

// ---------------------------------------------------------------------------
// Merge <=8 causal-split partials per q-row. grid = S blocks, block = DK.
// block index for (qt, c) = 16*g*(g+1) + (qt&31)*(g+1) + c, g = qt>>5.
// ---------------------------------------------------------------------------
__global__ __launch_bounds__(DK) void merge_kernel(
    const float* __restrict__ OP, const float* __restrict__ ML,
    float* __restrict__ out)
{
    const int row = blockIdx.x, dv = threadIdx.x;
    const int qt = row >> 4, ql = row & 15;
    const int g  = qt >> 5;
    const int base = 16 * g * (g + 1) + (qt & 31) * (g + 1);

    float M = -1e30f;
    for (int c = 0; c <= g; ++c)
        M = fmaxf(M, ML[((size_t)(base + c) * 16 + ql) * 2]);
    float L = 0.f, o = 0.f;
    for (int c = 0; c <= g; ++c) {
        const float mc = ML[((size_t)(base + c) * 16 + ql) * 2 + 0];
        const float lc = ML[((size_t)(base + c) * 16 + ql) * 2 + 1];
        const float wgt = __expf(mc - M);
        L += lc * wgt;
        o += wgt * OP[((size_t)(base + c) * 16 + ql) * DK + dv];
    }
    out[(size_t)row * DK + dv] = o / L;
}

// ---------------------------------------------------------------------------
extern "C" void kernel_launch(void* const* d_in, const int* in_sizes, int n_in,
                              void* d_out, int out_size, void* d_ws, size_t ws_size,
                              hipStream_t stream)
{
    (void)in_sizes; (void)n_in; (void)out_size; (void)ws_size;
    const float* X  = (const float*)d_in[0];
    const float* Wq = (const float*)d_in[1];
    const float* bq = (const float*)d_in[2];
    const float* Wk = (const float*)d_in[3];
    const float* bk = (const float*)d_in[4];
    const float* Wv = (const float*)d_in[5];
    const float* bv = (const float*)d_in[6];
    float* out = (float*)d_out;

    // workspace layout (~14.4 MB):
    //   Wb [384][1024] bf16 | Qb,Kb,Vb [S][DK] bf16 | Vt [DK][S] bf16 |
    //   { Xb [S][DMODEL] bf16  (dead after proj_gemm)
    //     OP [1152][16][DK] f32 + ML [1152][16][2] f32 }  <- aliased
    unsigned short* Wb = (unsigned short*)d_ws;
    unsigned short* Qb = Wb + (size_t)3 * DK * DMODEL;
    unsigned short* Kb = Qb + (size_t)S * DK;
    unsigned short* Vb = Kb + (size_t)S * DK;
    unsigned short* Vt = Vb + (size_t)S * DK;
    unsigned short* Xb = Vt + (size_t)S * DK;
    float* OP = (float*)Xb;                       // aliases Xb (sequential use)
    float* ML = OP + (size_t)1152 * 16 * DK;

    cvt_kernel<<<2240, 256, 0, stream>>>(X, Wq, Wk, Wv, Xb, Wb);
    proj_gemm<<<dim3(S / 16, 3), 256, 0, stream>>>(
        Xb, Wb, bq, bk, bv, Qb, Kb, Vb);
    transpose_v<<<dim3(S / 64, DK / 64), 256, 0, stream>>>(Vb, Vt);
    attn_mfma<<<1152, 64, 0, stream>>>(Qb, Kb, Vt, OP, ML);
    merge_kernel<<<S, DK, 0, stream>>>(OP, ML, out);
}

// Round 4
// 149.883 us; speedup vs baseline: 4.3213x; 1.0650x over previous
//
#include <hip/hip_runtime.h>
#include <hip/hip_bf16.h>

#define S 4096
#define DMODEL 1024
#define DK 128

typedef __attribute__((ext_vector_type(8))) short  short8;   // 8 x bf16 (4 VGPRs)
typedef __attribute__((ext_vector_type(4))) float  f32x4;    // MFMA accumulator

__device__ __forceinline__ unsigned short f2bf(float f) {
    return __builtin_bit_cast(unsigned short, __float2bfloat16(f));
}

__device__ __forceinline__ short8 cvt8(float4 a, float4 b) {
    short8 v;
    v[0] = (short)f2bf(a.x); v[1] = (short)f2bf(a.y);
    v[2] = (short)f2bf(a.z); v[3] = (short)f2bf(a.w);
    v[4] = (short)f2bf(b.x); v[5] = (short)f2bf(b.y);
    v[6] = (short)f2bf(b.z); v[7] = (short)f2bf(b.w);
    return v;
}

// ---------------------------------------------------------------------------
// Convert X [S][DMODEL] f32 -> Xb bf16; Wq|Wk|Wv [DK][DMODEL] f32 -> Wb bf16.
// One-shot, HBM-bound. 8 elems/thread. 573440 items / 8 / 256 = 2240 blocks.
// ---------------------------------------------------------------------------
__global__ __launch_bounds__(256) void cvt_kernel(
    const float* __restrict__ X,
    const float* __restrict__ Wq, const float* __restrict__ Wk,
    const float* __restrict__ Wv,
    unsigned short* __restrict__ Xb, unsigned short* __restrict__ Wb)
{
    const int i = blockIdx.x * 256 + threadIdx.x;
    const float* __restrict__ src;
    unsigned short* __restrict__ dst;
    size_t off;
    if (i < 524288) {
        src = X; dst = Xb; off = (size_t)i * 8;
    } else {
        const int j   = i - 524288;
        const int sel = j >> 14, jj = j & 16383;
        src = sel == 0 ? Wq : sel == 1 ? Wk : Wv;
        dst = Wb + (size_t)sel * DK * DMODEL;
        off = (size_t)jj * 8;
    }
    const float4 a = *(const float4*)(src + off);
    const float4 b = *(const float4*)(src + off + 4);
    *(short8*)(dst + off) = cvt8(a, b);
}

// ---------------------------------------------------------------------------
// QKV projection GEMM, bf16. grid = (S/16, 3), block = 128 (2 waves).
// Wave w: 16 rows x 64 cols (4 MFMA col-tiles). Per k-step: 1 A load +
// 4 B loads -> 4 independent MFMAs; unroll 4 = 20 loads / 16 MFMAs in flight.
// ---------------------------------------------------------------------------
__global__ __launch_bounds__(128) void proj_gemm(
    const unsigned short* __restrict__ Xb, const unsigned short* __restrict__ Wb,
    const float* __restrict__ bq, const float* __restrict__ bk,
    const float* __restrict__ bv,
    unsigned short* __restrict__ Qb, unsigned short* __restrict__ Kb,
    unsigned short* __restrict__ Vb)
{
    const int sel = blockIdx.y;
    const float* __restrict__ bias = sel == 0 ? bq : sel == 1 ? bk : bv;
    unsigned short* __restrict__ Out = sel == 0 ? Qb : sel == 1 ? Kb : Vb;
    const unsigned short* __restrict__ wbase = Wb + (size_t)sel * DK * DMODEL;

    const int tid = threadIdx.x, w = tid >> 6, lane = tid & 63;
    const int li = lane & 15, gl = lane >> 4;
    const int r0 = blockIdx.x * 16;
    const int n0 = w * 64;

    f32x4 acc[4];
    #pragma unroll
    for (int j = 0; j < 4; ++j)
        #pragma unroll
        for (int r = 0; r < 4; ++r) acc[j][r] = 0.f;

    const unsigned short* ap = &Xb[(size_t)(r0 + li) * DMODEL + 8 * gl];
    const unsigned short* bp0 = &wbase[(size_t)(n0 + li) * DMODEL + 8 * gl];
    const unsigned short* bp1 = bp0 + (size_t)16 * DMODEL;
    const unsigned short* bp2 = bp0 + (size_t)32 * DMODEL;
    const unsigned short* bp3 = bp0 + (size_t)48 * DMODEL;

    #pragma unroll 4
    for (int k0 = 0; k0 < DMODEL; k0 += 32) {
        const short8 a  = *(const short8*)(ap + k0);
        const short8 b0 = *(const short8*)(bp0 + k0);
        const short8 b1 = *(const short8*)(bp1 + k0);
        const short8 b2 = *(const short8*)(bp2 + k0);
        const short8 b3 = *(const short8*)(bp3 + k0);
        acc[0] = __builtin_amdgcn_mfma_f32_16x16x32_bf16(a, b0, acc[0], 0, 0, 0);
        acc[1] = __builtin_amdgcn_mfma_f32_16x16x32_bf16(a, b1, acc[1], 0, 0, 0);
        acc[2] = __builtin_amdgcn_mfma_f32_16x16x32_bf16(a, b2, acc[2], 0, 0, 0);
        acc[3] = __builtin_amdgcn_mfma_f32_16x16x32_bf16(a, b3, acc[3], 0, 0, 0);
    }

    #pragma unroll
    for (int j = 0; j < 4; ++j)
        #pragma unroll
        for (int r = 0; r < 4; ++r) {
            const int row = r0 + 4 * gl + r;
            const int col = n0 + 16 * j + li;
            Out[(size_t)row * DK + col] = f2bf(acc[j][r] + bias[col]);
        }
}

// ---------------------------------------------------------------------------
// V [S][DK] bf16 -> Vt [DK][S] bf16 (coalesced LDS tile transpose).
// ---------------------------------------------------------------------------
__global__ __launch_bounds__(256) void transpose_v(
    const unsigned short* __restrict__ Vb, unsigned short* __restrict__ Vt)
{
    __shared__ unsigned short tile[64][72];   // +8 pad
    const int s0 = blockIdx.x * 64, d0 = blockIdx.y * 64;
    const int t = threadIdx.x;
    const int r = t >> 2, cc = (t & 3) * 16;

    const short8* src = (const short8*)&Vb[(size_t)(s0 + r) * DK + d0 + cc];
    const short8 a = src[0], b = src[1];
    #pragma unroll
    for (int i = 0; i < 8; ++i) {
        tile[r][cc + i]     = (unsigned short)a[i];
        tile[r][cc + 8 + i] = (unsigned short)b[i];
    }
    __syncthreads();

    short8 o0, o1;
    #pragma unroll
    for (int i = 0; i < 8; ++i) {
        o0[i] = (short)tile[cc + i][r];
        o1[i] = (short)tile[cc + 8 + i][r];
    }
    short8* dst = (short8*)&Vt[(size_t)(d0 + r) * S + s0 + cc];
    dst[0] = o0; dst[1] = o1;
}

// ---------------------------------------------------------------------------
// Flash attention, bf16 MFMA. 1 wave/block, 32 q-rows/wave (2 A-frag sets),
// chunk = 256 keys. q-tile t (32 rows, group g=t>>3) gets g+1 chunks ->
// 1088 blocks. Per 32-key iter: 8 K loads (shared by both q-sets, register
// double-buffered one iter ahead) + 8 V loads + 16 QK MFMA + softmax
// (defer-max, THR=6) + LDS P-bounce + 16 PV MFMA.
// ---------------------------------------------------------------------------
__global__ __launch_bounds__(64) void attn_mfma(
    const unsigned short* __restrict__ Qb,
    const unsigned short* __restrict__ Kb,
    const unsigned short* __restrict__ Vt,
    float* __restrict__ OP, float* __restrict__ ML)
{
    const int b = blockIdx.x;
    int g = 0;
    while (4 * (g + 1) * (g + 2) <= b) ++g;        // <=15 scalar iters
    const int off = b - 4 * g * (g + 1);
    const int t   = 8 * g + off / (g + 1);
    const int c   = off % (g + 1);
    const int kstart = c * 256;
    const int kend   = min((c + 1) * 256, 32 * t + 32);

    const int lane = threadIdx.x, li = lane & 15, gl = lane >> 4;

    __shared__ unsigned short Pl[32][40];   // 80B rows; b128 reads 16B-aligned

    short8 aq[2][4];
    #pragma unroll
    for (int qs = 0; qs < 2; ++qs)
        #pragma unroll
        for (int s = 0; s < 4; ++s)
            aq[qs][s] = *(const short8*)
                &Qb[(size_t)(32 * t + 16 * qs + li) * DK + 32 * s + 8 * gl];

    f32x4 accv[2][8];
    #pragma unroll
    for (int qs = 0; qs < 2; ++qs)
        #pragma unroll
        for (int n = 0; n < 8; ++n)
            #pragma unroll
            for (int r = 0; r < 4; ++r) accv[qs][n][r] = 0.f;

    float mrow[2][4], lrow[2][4];
    #pragma unroll
    for (int qs = 0; qs < 2; ++qs)
        #pragma unroll
        for (int r = 0; r < 4; ++r) { mrow[qs][r] = -1e30f; lrow[qs][r] = 0.f; }

    const float scale = 0.08838834764831845f;  // 1/sqrt(128)

    // ---- K register double-buffer: preload first tile
    short8 bkc[2][4], bkn[2][4];
    #pragma unroll
    for (int kt = 0; kt < 2; ++kt)
        #pragma unroll
        for (int s = 0; s < 4; ++s)
            bkc[kt][s] = *(const short8*)
                &Kb[(size_t)(kstart + 16 * kt + li) * DK + 32 * s + 8 * gl];

    for (int kb = kstart; kb < kend; kb += 32) {
        // ---- V loads for THIS iter (consumed after softmax: natural slack)
        short8 bv[8];
        #pragma unroll
        for (int n = 0; n < 8; ++n)
            bv[n] = *(const short8*)&Vt[(size_t)(16 * n + li) * S + kb + 8 * gl];

        // ---- QK^T with current K
        f32x4 sc[2][2];
        #pragma unroll
        for (int qs = 0; qs < 2; ++qs)
            #pragma unroll
            for (int kt = 0; kt < 2; ++kt)
                #pragma unroll
                for (int r = 0; r < 4; ++r) sc[qs][kt][r] = 0.f;
        __builtin_amdgcn_s_setprio(1);
        #pragma unroll
        for (int qs = 0; qs < 2; ++qs)
            #pragma unroll
            for (int kt = 0; kt < 2; ++kt)
                #pragma unroll
                for (int s = 0; s < 4; ++s)
                    sc[qs][kt] = __builtin_amdgcn_mfma_f32_16x16x32_bf16(
                        aq[qs][s], bkc[kt][s], sc[qs][kt], 0, 0, 0);
        __builtin_amdgcn_s_setprio(0);

        // ---- prefetch NEXT iter's K (clamped address; hides L2 latency)
        const int kn = (kb + 32 < kend) ? kb + 32 : kb;
        #pragma unroll
        for (int kt = 0; kt < 2; ++kt)
            #pragma unroll
            for (int s = 0; s < 4; ++s)
                bkn[kt][s] = *(const short8*)
                    &Kb[(size_t)(kn + 16 * kt + li) * DK + 32 * s + 8 * gl];

        // ---- scale + causal mask in place (row q = 4*gl+r, col key = li)
        #pragma unroll
        for (int qs = 0; qs < 2; ++qs)
            #pragma unroll
            for (int kt = 0; kt < 2; ++kt)
                #pragma unroll
                for (int r = 0; r < 4; ++r) {
                    const int key = kb + 16 * kt + li;
                    const int q   = 32 * t + 16 * qs + 4 * gl + r;
                    sc[qs][kt][r] = (key > q) ? -1e30f : sc[qs][kt][r] * scale;
                }

        // ---- per-row tile max (4-step shfl chains; 8 independent chains)
        float tm[2][4];
        #pragma unroll
        for (int qs = 0; qs < 2; ++qs)
            #pragma unroll
            for (int r = 0; r < 4; ++r) {
                float v = fmaxf(sc[qs][0][r], sc[qs][1][r]);
                v = fmaxf(v, __shfl_xor(v, 1));
                v = fmaxf(v, __shfl_xor(v, 2));
                v = fmaxf(v, __shfl_xor(v, 4));
                v = fmaxf(v, __shfl_xor(v, 8));
                tm[qs][r] = v;
            }

        // ---- defer-max: only rescale when a row's max grew past THR=6
        int need = 0;
        #pragma unroll
        for (int qs = 0; qs < 2; ++qs)
            #pragma unroll
            for (int r = 0; r < 4; ++r)
                need |= (tm[qs][r] > mrow[qs][r] + 6.f) ? 1 : 0;
        if (__any(need)) {
            #pragma unroll
            for (int qs = 0; qs < 2; ++qs)
                #pragma unroll
                for (int r = 0; r < 4; ++r) {
                    const float mnew = fmaxf(mrow[qs][r], tm[qs][r]);
                    const float corr = __expf(mrow[qs][r] - mnew);
                    lrow[qs][r] *= corr;
                    mrow[qs][r] = mnew;
                    #pragma unroll
                    for (int n = 0; n < 8; ++n) accv[qs][n][r] *= corr;
                }
        }

        // ---- exp + row-sum
        #pragma unroll
        for (int qs = 0; qs < 2; ++qs)
            #pragma unroll
            for (int r = 0; r < 4; ++r) {
                const float p0 = __expf(sc[qs][0][r] - mrow[qs][r]);
                const float p1 = __expf(sc[qs][1][r] - mrow[qs][r]);
                sc[qs][0][r] = p0; sc[qs][1][r] = p1;
                float ps = p0 + p1;
                ps += __shfl_xor(ps, 1);
                ps += __shfl_xor(ps, 2);
                ps += __shfl_xor(ps, 4);
                ps += __shfl_xor(ps, 8);
                lrow[qs][r] += ps;
            }

        // ---- P (D-layout) -> LDS bf16 -> A-fragments
        #pragma unroll
        for (int qs = 0; qs < 2; ++qs)
            #pragma unroll
            for (int kt = 0; kt < 2; ++kt)
                #pragma unroll
                for (int r = 0; r < 4; ++r)
                    Pl[16 * qs + 4 * gl + r][16 * kt + li] = f2bf(sc[qs][kt][r]);
        __syncthreads();
        const short8 pa0 = *(const short8*)&Pl[li][8 * gl];
        const short8 pa1 = *(const short8*)&Pl[16 + li][8 * gl];
        __syncthreads();

        // ---- PV
        __builtin_amdgcn_s_setprio(1);
        #pragma unroll
        for (int n = 0; n < 8; ++n) {
            accv[0][n] = __builtin_amdgcn_mfma_f32_16x16x32_bf16(pa0, bv[n], accv[0][n], 0, 0, 0);
            accv[1][n] = __builtin_amdgcn_mfma_f32_16x16x32_bf16(pa1, bv[n], accv[1][n], 0, 0, 0);
        }
        __builtin_amdgcn_s_setprio(0);

        // ---- rotate K buffers
        #pragma unroll
        for (int kt = 0; kt < 2; ++kt)
            #pragma unroll
            for (int s = 0; s < 4; ++s) bkc[kt][s] = bkn[kt][s];
    }

    // ---- store unnormalized partial O + (m, l)
    #pragma unroll
    for (int qs = 0; qs < 2; ++qs)
        #pragma unroll
        for (int n = 0; n < 8; ++n)
            #pragma unroll
            for (int r = 0; r < 4; ++r)
                OP[((size_t)b * 32 + 16 * qs + 4 * gl + r) * DK + 16 * n + li]
                    = accv[qs][n][r];
    if (li == 0) {
        #pragma unroll
        for (int qs = 0; qs < 2; ++qs)
            #pragma unroll
            for (int r = 0; r < 4; ++r) {
                ML[((size_t)b * 32 + 16 * qs + 4 * gl + r) * 2 + 0] = mrow[qs][r];
                ML[((size_t)b * 32 + 16 * qs + 4 * gl + r) * 2 + 1] = lrow[qs][r];
            }
    }
}

// ---------------------------------------------------------------------------
// Merge <=16 causal-split partials per q-row. grid = S blocks, block = DK.
// Block index for 32-row tile t, chunk c: 4g(g+1) + (t&7)(g+1) + c, g = t>>3.
// ---------------------------------------------------------------------------
__global__ __launch_bounds__(DK) void merge_kernel(
    const float* __restrict__ OP, const float* __restrict__ ML,
    float* __restrict__ out)
{
    const int row = blockIdx.x, dv = threadIdx.x;
    const int t  = row >> 5, rl = row & 31;
    const int g  = t >> 3;
    const int base = 4 * g * (g + 1) + (t & 7) * (g + 1);

    float M = -1e30f;
    for (int c = 0; c <= g; ++c)
        M = fmaxf(M, ML[((size_t)(base + c) * 32 + rl) * 2]);
    float L = 0.f, o = 0.f;
    for (int c = 0; c <= g; ++c) {
        const float mc = ML[((size_t)(base + c) * 32 + rl) * 2 + 0];
        const float lc = ML[((size_t)(base + c) * 32 + rl) * 2 + 1];
        const float wgt = __expf(mc - M);
        L += lc * wgt;
        o += wgt * OP[((size_t)(base + c) * 32 + rl) * DK + dv];
    }
    out[(size_t)row * DK + dv] = o / L;
}

// ---------------------------------------------------------------------------
extern "C" void kernel_launch(void* const* d_in, const int* in_sizes, int n_in,
                              void* d_out, int out_size, void* d_ws, size_t ws_size,
                              hipStream_t stream)
{
    (void)in_sizes; (void)n_in; (void)out_size; (void)ws_size;
    const float* X  = (const float*)d_in[0];
    const float* Wq = (const float*)d_in[1];
    const float* bq = (const float*)d_in[2];
    const float* Wk = (const float*)d_in[3];
    const float* bk = (const float*)d_in[4];
    const float* Wv = (const float*)d_in[5];
    const float* bv = (const float*)d_in[6];
    float* out = (float*)d_out;

    // workspace (~23 MB): Wb | Qb | Kb | Vb | Vt | { Xb (dead after proj) /
    // OP [1088][32][DK] f32 + ML [1088][32][2] f32 }  <- aliased region
    unsigned short* Wb = (unsigned short*)d_ws;
    unsigned short* Qb = Wb + (size_t)3 * DK * DMODEL;
    unsigned short* Kb = Qb + (size_t)S * DK;
    unsigned short* Vb = Kb + (size_t)S * DK;
    unsigned short* Vt = Vb + (size_t)S * DK;
    unsigned short* Xb = Vt + (size_t)S * DK;
    float* OP = (float*)Xb;                      // aliases Xb (sequential use)
    float* ML = OP + (size_t)1088 * 32 * DK;

    cvt_kernel<<<2240, 256, 0, stream>>>(X, Wq, Wk, Wv, Xb, Wb);
    proj_gemm<<<dim3(S / 16, 3), 128, 0, stream>>>(
        Xb, Wb, bq, bk, bv, Qb, Kb, Vb);
    transpose_v<<<dim3(S / 64, DK / 64), 256, 0, stream>>>(Vb, Vt);
    attn_mfma<<<1088, 64, 0, stream>>>(Qb, Kb, Vt, OP, ML);
    merge_kernel<<<S, DK, 0, stream>>>(OP, ML, out);
}